// Round 1
// baseline (598.708 us; speedup 1.0000x reference)
//
#include <hip/hip_runtime.h>

#define D 128
#define KOUT 100

// ---------------- CSR build ----------------

__global__ void init_kernel(int* __restrict__ deg, int* __restrict__ cursor, int n) {
    int i = blockIdx.x * blockDim.x + threadIdx.x;
    if (i < n) { deg[i] = 1; cursor[i] = 0; }   // deg starts at 1 for self-loop
}

__global__ void count_kernel(const int* __restrict__ ei, int* __restrict__ deg, int E) {
    int e = blockIdx.x * blockDim.x + threadIdx.x;
    if (e < E) {
        int d = ei[E + e];          // dst row
        atomicAdd(&deg[d], 1);
    }
}

__global__ void dinv_kernel(const int* __restrict__ deg, float* __restrict__ dinv, int n) {
    int i = blockIdx.x * blockDim.x + threadIdx.x;
    if (i < n) dinv[i] = rsqrtf((float)deg[i]);   // deg >= 1 always (self-loop)
}

// exclusive scan of counts (deg[i]-1) -> rowptr, 1024 elems per block
__global__ void scan_block_kernel(const int* __restrict__ deg, int* __restrict__ rowptr,
                                  int* __restrict__ bsums, int n) {
    __shared__ int sd[256];
    int tid = threadIdx.x;
    int base = blockIdx.x * 1024 + tid * 4;
    int v[4];
    int sum = 0;
#pragma unroll
    for (int q = 0; q < 4; q++) {
        int idx = base + q;
        int c = (idx < n) ? (deg[idx] - 1) : 0;
        v[q] = sum;
        sum += c;
    }
    sd[tid] = sum;
    __syncthreads();
    for (int off = 1; off < 256; off <<= 1) {
        int t = (tid >= off) ? sd[tid - off] : 0;
        __syncthreads();
        sd[tid] += t;
        __syncthreads();
    }
    int excl = sd[tid] - sum;
#pragma unroll
    for (int q = 0; q < 4; q++) {
        int idx = base + q;
        if (idx < n) rowptr[idx] = excl + v[q];
    }
    if (tid == 255) bsums[blockIdx.x] = sd[255];
}

__global__ void scan_total_kernel(int* __restrict__ bsums, int nb) {
    if (threadIdx.x == 0 && blockIdx.x == 0) {
        int run = 0;
        for (int b = 0; b < nb; b++) { int t = bsums[b]; bsums[b] = run; run += t; }
    }
}

__global__ void scan_add_kernel(int* __restrict__ rowptr, const int* __restrict__ bsums, int n) {
    int i = blockIdx.x * blockDim.x + threadIdx.x;
    if (i < n) rowptr[i] += bsums[i >> 10];
}

__global__ void scatter_kernel(const int* __restrict__ ei, const int* __restrict__ rowptr,
                               int* __restrict__ cursor, int* __restrict__ csr, int E) {
    int e = blockIdx.x * blockDim.x + threadIdx.x;
    if (e < E) {
        int s = ei[e];
        int d = ei[E + e];
        int p = atomicAdd(&cursor[d], 1);
        csr[rowptr[d] + p] = s;
    }
}

__global__ void prep_wa_kernel(const float* __restrict__ Wa, const float* __restrict__ ba,
                               float* __restrict__ wpad, float* __restrict__ bpad) {
    int idx = blockIdx.x * blockDim.x + threadIdx.x;
    if (idx < 128 * 128) {
        int k = idx >> 7, j = idx & 127;
        wpad[idx] = (j < KOUT) ? Wa[k * KOUT + j] : 0.f;
    }
    if (idx < 128) bpad[idx] = (idx < KOUT) ? ba[idx] : 0.f;
}

// ---------------- GEMM: Y[n,128] = X[n,128] @ W[128,128] (+bias) ----------------
// block 256 threads, tile 64 rows x 128 cols; thread = 8 rows x 4 cols

__device__ inline void fma4(float4& a, float s, const float4& w) {
    a.x = fmaf(s, w.x, a.x);
    a.y = fmaf(s, w.y, a.y);
    a.z = fmaf(s, w.z, a.z);
    a.w = fmaf(s, w.w, a.w);
}

__launch_bounds__(256)
__global__ void gemm128_kernel(const float* __restrict__ X, const float* __restrict__ W,
                               const float* __restrict__ bias, float* __restrict__ Y, int nrows) {
    __shared__ float Xs[64 * 128];
    int tid = threadIdx.x;
    int tx = tid & 31;       // col group: cols 4*tx .. 4*tx+3
    int ty = tid >> 5;       // row group: rows 8*ty .. 8*ty+7
    int r0 = blockIdx.x * 64;

    const float4* X4 = (const float4*)X;
    float4* Xs4 = (float4*)Xs;
#pragma unroll
    for (int it = 0; it < 8; it++) {
        int q = it * 256 + tid;
        int row = q >> 5, c4 = q & 31;
        float4 val = make_float4(0.f, 0.f, 0.f, 0.f);
        if (r0 + row < nrows) val = X4[(size_t)(r0 + row) * 32 + c4];
        Xs4[q] = val;
    }
    __syncthreads();

    const float4* W4 = (const float4*)W;
    float4 acc[8];
#pragma unroll
    for (int r = 0; r < 8; r++) acc[r] = make_float4(0.f, 0.f, 0.f, 0.f);

    for (int k = 0; k < 128; k += 4) {
        float4 w0 = W4[(k + 0) * 32 + tx];
        float4 w1 = W4[(k + 1) * 32 + tx];
        float4 w2 = W4[(k + 2) * 32 + tx];
        float4 w3 = W4[(k + 3) * 32 + tx];
#pragma unroll
        for (int r = 0; r < 8; r++) {
            float4 xv = Xs4[(ty * 8 + r) * 32 + (k >> 2)];
            fma4(acc[r], xv.x, w0);
            fma4(acc[r], xv.y, w1);
            fma4(acc[r], xv.z, w2);
            fma4(acc[r], xv.w, w3);
        }
    }

    float4 bb = make_float4(0.f, 0.f, 0.f, 0.f);
    if (bias) bb = ((const float4*)bias)[tx];
#pragma unroll
    for (int r = 0; r < 8; r++) {
        int row = r0 + ty * 8 + r;
        if (row < nrows) {
            float4 o;
            o.x = acc[r].x + bb.x;
            o.y = acc[r].y + bb.y;
            o.z = acc[r].z + bb.z;
            o.w = acc[r].w + bb.w;
            ((float4*)Y)[(size_t)row * 32 + tx] = o;
        }
    }
}

// ---------------- Aggregate: O[i] = sum_{e:dst=i} H[src]*norm + H[i]*dinv^2 + b ----------------
// one wave per node, lane handles float2 of D

__launch_bounds__(256)
__global__ void aggregate_kernel(const float* __restrict__ H, const int* __restrict__ csr,
                                 const int* __restrict__ rowptr, const int* __restrict__ deg,
                                 const float* __restrict__ dinv, const float* __restrict__ bias,
                                 float* __restrict__ O, int n, int do_relu) {
    int wid = threadIdx.x >> 6, lane = threadIdx.x & 63;
    int i = blockIdx.x * 4 + wid;
    if (i >= n) return;

    const float2* H2 = (const float2*)H;
    float di = dinv[i];
    float2 hv = H2[(size_t)i * 64 + lane];
    float sl = di * di;
    float ax = hv.x * sl, ay = hv.y * sl;

    int start = rowptr[i];
    int cnt = deg[i] - 1;
    int e = 0;
    for (; e + 1 < cnt; e += 2) {
        int s0 = csr[start + e];
        int s1 = csr[start + e + 1];
        float n0 = dinv[s0] * di;
        float n1 = dinv[s1] * di;
        float2 h0 = H2[(size_t)s0 * 64 + lane];
        float2 h1 = H2[(size_t)s1 * 64 + lane];
        ax = fmaf(h0.x, n0, ax); ay = fmaf(h0.y, n0, ay);
        ax = fmaf(h1.x, n1, ax); ay = fmaf(h1.y, n1, ay);
    }
    if (e < cnt) {
        int s0 = csr[start + e];
        float n0 = dinv[s0] * di;
        float2 h0 = H2[(size_t)s0 * 64 + lane];
        ax = fmaf(h0.x, n0, ax); ay = fmaf(h0.y, n0, ay);
    }

    float2 b = ((const float2*)bias)[lane];
    ax += b.x; ay += b.y;
    if (do_relu) { ax = fmaxf(ax, 0.f); ay = fmaxf(ay, 0.f); }
    float2 o; o.x = ax; o.y = ay;
    ((float2*)O)[(size_t)i * 64 + lane] = o;
}

// ---------------- Softmax over K=100 (logits stored padded to 128) ----------------

__launch_bounds__(256)
__global__ void softmax_kernel(const float* __restrict__ L, float* __restrict__ O, int n) {
    int wid = threadIdx.x >> 6, lane = threadIdx.x & 63;
    int row = blockIdx.x * 4 + wid;
    if (row >= n) return;
    const float* lr = L + (size_t)row * 128;
    float v0 = (lane < KOUT) ? lr[lane] : -1e30f;
    float v1 = (lane + 64 < KOUT) ? lr[lane + 64] : -1e30f;
    float m = fmaxf(v0, v1);
    for (int off = 32; off > 0; off >>= 1) m = fmaxf(m, __shfl_xor(m, off));
    float e0 = (lane < KOUT) ? __expf(v0 - m) : 0.f;
    float e1 = (lane + 64 < KOUT) ? __expf(v1 - m) : 0.f;
    float s = e0 + e1;
    for (int off = 32; off > 0; off >>= 1) s += __shfl_xor(s, off);
    float inv = 1.f / s;
    if (lane < KOUT) O[(size_t)row * KOUT + lane] = e0 * inv;
    if (lane + 64 < KOUT) O[(size_t)row * KOUT + lane + 64] = e1 * inv;
}

// ---------------- launch ----------------

extern "C" void kernel_launch(void* const* d_in, const int* in_sizes, int n_in,
                              void* d_out, int out_size, void* d_ws, size_t ws_size,
                              hipStream_t stream) {
    const float* x  = (const float*)d_in[0];
    const int*   ei = (const int*)d_in[1];     // [2,E] int32 (JAX x64-off)
    const float* W1 = (const float*)d_in[2];
    const float* b1 = (const float*)d_in[3];
    const float* W2 = (const float*)d_in[4];
    const float* b2 = (const float*)d_in[5];
    const float* Wa = (const float*)d_in[6];
    const float* ba = (const float*)d_in[7];
    float* out = (float*)d_out;

    int N = in_sizes[0] / D;
    int E = in_sizes[1] / 2;

    char* w = (char*)d_ws;
    size_t off = 0;
    auto carve = [&](size_t bytes) -> void* {
        void* p = w + off;
        off = (off + bytes + 255) & ~(size_t)255;
        return p;
    };
    int*   deg    = (int*)carve((size_t)N * 4);
    int*   cursor = (int*)carve((size_t)N * 4);
    float* dinv   = (float*)carve((size_t)N * 4);
    int*   rowptr = (int*)carve((size_t)N * 4);
    int*   bsums  = (int*)carve(1024);
    int*   csr    = (int*)carve((size_t)E * 4);
    float* wpad   = (float*)carve(128 * 128 * 4);
    float* bpad   = (float*)carve(512);
    float* bufA   = (float*)carve((size_t)N * D * 4);
    float* bufB   = (float*)carve((size_t)N * D * 4);
    (void)ws_size; (void)n_in; (void)out_size;

    int nbN = (N + 255) / 256;
    int nbE = (E + 255) / 256;
    int nbScan = (N + 1023) / 1024;
    int nbNode4 = (N + 3) / 4;
    int nbGemm = (N + 63) / 64;

    init_kernel<<<nbN, 256, 0, stream>>>(deg, cursor, N);
    count_kernel<<<nbE, 256, 0, stream>>>(ei, deg, E);
    dinv_kernel<<<nbN, 256, 0, stream>>>(deg, dinv, N);
    scan_block_kernel<<<nbScan, 256, 0, stream>>>(deg, rowptr, bsums, N);
    scan_total_kernel<<<1, 64, 0, stream>>>(bsums, nbScan);
    scan_add_kernel<<<nbN, 256, 0, stream>>>(rowptr, bsums, N);
    scatter_kernel<<<nbE, 256, 0, stream>>>(ei, rowptr, cursor, csr, E);
    prep_wa_kernel<<<64, 256, 0, stream>>>(Wa, ba, wpad, bpad);

    // layer 1: lin -> aggregate(+b1) -> relu
    gemm128_kernel<<<nbGemm, 256, 0, stream>>>(x, W1, nullptr, bufA, N);
    aggregate_kernel<<<nbNode4, 256, 0, stream>>>(bufA, csr, rowptr, deg, dinv, b1, bufB, N, 1);
    // layer 2
    gemm128_kernel<<<nbGemm, 256, 0, stream>>>(bufB, W2, nullptr, bufA, N);
    aggregate_kernel<<<nbNode4, 256, 0, stream>>>(bufA, csr, rowptr, deg, dinv, b2, bufB, N, 0);
    // attention logits (padded to 128 cols) + softmax
    gemm128_kernel<<<nbGemm, 256, 0, stream>>>(bufB, wpad, bpad, bufA, N);
    softmax_kernel<<<nbNode4, 256, 0, stream>>>(bufA, out, N);
}

// Round 2
// 498.372 us; speedup vs baseline: 1.2013x; 1.2013x over previous
//
#include <hip/hip_runtime.h>

#define D 128
#define KOUT 100

// ---------------- bf16 pack/unpack helpers ----------------
// uint holds feature pair: low 16 bits = even feature, high 16 = odd feature.

__device__ inline float bf_lo(unsigned int u) { return __uint_as_float(u << 16); }
__device__ inline float bf_hi(unsigned int u) { return __uint_as_float(u & 0xFFFF0000u); }

__device__ inline unsigned int pack_bf(float a, float b) {
    unsigned int ua = __float_as_uint(a);
    unsigned int ub = __float_as_uint(b);
    ua = ua + 0x7FFFu + ((ua >> 16) & 1u);   // RNE
    ub = ub + 0x7FFFu + ((ub >> 16) & 1u);
    return (ua >> 16) | (ub & 0xFFFF0000u);
}

// ---------------- CSR build ----------------

__global__ void init_kernel(int* __restrict__ deg, int* __restrict__ cursor, int n) {
    int i = blockIdx.x * blockDim.x + threadIdx.x;
    if (i < n) { deg[i] = 1; cursor[i] = 0; }   // deg starts at 1 for self-loop
}

__global__ void count_kernel(const int* __restrict__ ei, int* __restrict__ deg, int E) {
    int e = blockIdx.x * blockDim.x + threadIdx.x;
    if (e < E) {
        int d = ei[E + e];          // dst row
        atomicAdd(&deg[d], 1);
    }
}

__global__ void dinv_kernel(const int* __restrict__ deg, float* __restrict__ dinv, int n) {
    int i = blockIdx.x * blockDim.x + threadIdx.x;
    if (i < n) dinv[i] = rsqrtf((float)deg[i]);   // deg >= 1 always (self-loop)
}

// exclusive scan of counts (deg[i]-1) -> rowptr, 1024 elems per block
__global__ void scan_block_kernel(const int* __restrict__ deg, int* __restrict__ rowptr,
                                  int* __restrict__ bsums, int n) {
    __shared__ int sd[256];
    int tid = threadIdx.x;
    int base = blockIdx.x * 1024 + tid * 4;
    int v[4];
    int sum = 0;
#pragma unroll
    for (int q = 0; q < 4; q++) {
        int idx = base + q;
        int c = (idx < n) ? (deg[idx] - 1) : 0;
        v[q] = sum;
        sum += c;
    }
    sd[tid] = sum;
    __syncthreads();
    for (int off = 1; off < 256; off <<= 1) {
        int t = (tid >= off) ? sd[tid - off] : 0;
        __syncthreads();
        sd[tid] += t;
        __syncthreads();
    }
    int excl = sd[tid] - sum;
#pragma unroll
    for (int q = 0; q < 4; q++) {
        int idx = base + q;
        if (idx < n) rowptr[idx] = excl + v[q];
    }
    if (tid == 255) bsums[blockIdx.x] = sd[255];
}

__global__ void scan_total_kernel(int* __restrict__ bsums, int nb) {
    if (threadIdx.x == 0 && blockIdx.x == 0) {
        int run = 0;
        for (int b = 0; b < nb; b++) { int t = bsums[b]; bsums[b] = run; run += t; }
    }
}

__global__ void scan_add_kernel(int* __restrict__ rowptr, const int* __restrict__ bsums, int n) {
    int i = blockIdx.x * blockDim.x + threadIdx.x;
    if (i < n) rowptr[i] += bsums[i >> 10];
}

__global__ void scatter_kernel(const int* __restrict__ ei, const int* __restrict__ rowptr,
                               int* __restrict__ cursor, const float* __restrict__ dinv,
                               int* __restrict__ csr, float* __restrict__ wnorm, int E) {
    int e = blockIdx.x * blockDim.x + threadIdx.x;
    if (e < E) {
        int s = ei[e];
        int d = ei[E + e];
        int p = atomicAdd(&cursor[d], 1);
        int q = rowptr[d] + p;
        csr[q] = s;
        wnorm[q] = dinv[s] * dinv[d];
    }
}

__global__ void prep_wa_kernel(const float* __restrict__ Wa, const float* __restrict__ ba,
                               float* __restrict__ wpad, float* __restrict__ bpad) {
    int idx = blockIdx.x * blockDim.x + threadIdx.x;
    if (idx < 128 * 128) {
        int k = idx >> 7, j = idx & 127;
        wpad[idx] = (j < KOUT) ? Wa[k * KOUT + j] : 0.f;
    }
    if (idx < 128) bpad[idx] = (idx < KOUT) ? ba[idx] : 0.f;
}

// ---------------- GEMM: Y[n,128] = X[n,128] @ W[128,128] (+bias) ----------------
// block 256 threads, tile 64 rows x 128 cols; thread = 8 rows x 4 cols
// out_bf16: store as packed bf16 pairs (uint2 per thread-col-group) for gather layers

__device__ inline void fma4(float4& a, float s, const float4& w) {
    a.x = fmaf(s, w.x, a.x);
    a.y = fmaf(s, w.y, a.y);
    a.z = fmaf(s, w.z, a.z);
    a.w = fmaf(s, w.w, a.w);
}

__launch_bounds__(256)
__global__ void gemm128_kernel(const float* __restrict__ X, const float* __restrict__ W,
                               const float* __restrict__ bias, void* __restrict__ Y,
                               int nrows, int out_bf16) {
    __shared__ float Xs[64 * 128];
    int tid = threadIdx.x;
    int tx = tid & 31;       // col group: cols 4*tx .. 4*tx+3
    int ty = tid >> 5;       // row group: rows 8*ty .. 8*ty+7
    int r0 = blockIdx.x * 64;

    const float4* X4 = (const float4*)X;
    float4* Xs4 = (float4*)Xs;
#pragma unroll
    for (int it = 0; it < 8; it++) {
        int q = it * 256 + tid;
        int row = q >> 5, c4 = q & 31;
        float4 val = make_float4(0.f, 0.f, 0.f, 0.f);
        if (r0 + row < nrows) val = X4[(size_t)(r0 + row) * 32 + c4];
        Xs4[q] = val;
    }
    __syncthreads();

    const float4* W4 = (const float4*)W;
    float4 acc[8];
#pragma unroll
    for (int r = 0; r < 8; r++) acc[r] = make_float4(0.f, 0.f, 0.f, 0.f);

    for (int k = 0; k < 128; k += 4) {
        float4 w0 = W4[(k + 0) * 32 + tx];
        float4 w1 = W4[(k + 1) * 32 + tx];
        float4 w2 = W4[(k + 2) * 32 + tx];
        float4 w3 = W4[(k + 3) * 32 + tx];
#pragma unroll
        for (int r = 0; r < 8; r++) {
            float4 xv = Xs4[(ty * 8 + r) * 32 + (k >> 2)];
            fma4(acc[r], xv.x, w0);
            fma4(acc[r], xv.y, w1);
            fma4(acc[r], xv.z, w2);
            fma4(acc[r], xv.w, w3);
        }
    }

    float4 bb = make_float4(0.f, 0.f, 0.f, 0.f);
    if (bias) bb = ((const float4*)bias)[tx];
#pragma unroll
    for (int r = 0; r < 8; r++) {
        int row = r0 + ty * 8 + r;
        if (row < nrows) {
            float4 o;
            o.x = acc[r].x + bb.x;
            o.y = acc[r].y + bb.y;
            o.z = acc[r].z + bb.z;
            o.w = acc[r].w + bb.w;
            if (out_bf16) {
                uint2 u;
                u.x = pack_bf(o.x, o.y);
                u.y = pack_bf(o.z, o.w);
                ((uint2*)Y)[(size_t)row * 32 + tx] = u;
            } else {
                ((float4*)Y)[(size_t)row * 32 + tx] = o;
            }
        }
    }
}

// ---------------- Aggregate: O[i] = sum_{e:dst=i} Hb[src]*wnorm + Hb[i]*dinv^2 + b ----------
// one wave per node; H stored bf16-packed (uint per 2 features), lane = 1 uint = 2 feats
// f32 accumulate; wnorm precomputed per CSR slot (sequential read)

__launch_bounds__(256)
__global__ void aggregate_kernel(const unsigned int* __restrict__ Hb, const int* __restrict__ csr,
                                 const float* __restrict__ wnorm,
                                 const int* __restrict__ rowptr, const int* __restrict__ deg,
                                 const float* __restrict__ dinv, const float* __restrict__ bias,
                                 float* __restrict__ O, int n, int do_relu) {
    int wid = threadIdx.x >> 6, lane = threadIdx.x & 63;
    int i = blockIdx.x * 4 + wid;
    if (i >= n) return;

    float di = dinv[i];
    float sl = di * di;
    unsigned int us = Hb[(size_t)i * 64 + lane];
    float ax = bf_lo(us) * sl;
    float ay = bf_hi(us) * sl;

    int start = rowptr[i];
    int cnt = deg[i] - 1;
    int e = 0;
    for (; e + 3 < cnt; e += 4) {
        int s0 = csr[start + e];
        int s1 = csr[start + e + 1];
        int s2 = csr[start + e + 2];
        int s3 = csr[start + e + 3];
        float n0 = wnorm[start + e];
        float n1 = wnorm[start + e + 1];
        float n2 = wnorm[start + e + 2];
        float n3 = wnorm[start + e + 3];
        unsigned int u0 = Hb[(size_t)s0 * 64 + lane];
        unsigned int u1 = Hb[(size_t)s1 * 64 + lane];
        unsigned int u2 = Hb[(size_t)s2 * 64 + lane];
        unsigned int u3 = Hb[(size_t)s3 * 64 + lane];
        ax = fmaf(bf_lo(u0), n0, ax); ay = fmaf(bf_hi(u0), n0, ay);
        ax = fmaf(bf_lo(u1), n1, ax); ay = fmaf(bf_hi(u1), n1, ay);
        ax = fmaf(bf_lo(u2), n2, ax); ay = fmaf(bf_hi(u2), n2, ay);
        ax = fmaf(bf_lo(u3), n3, ax); ay = fmaf(bf_hi(u3), n3, ay);
    }
    for (; e < cnt; e++) {
        int s0 = csr[start + e];
        float n0 = wnorm[start + e];
        unsigned int u0 = Hb[(size_t)s0 * 64 + lane];
        ax = fmaf(bf_lo(u0), n0, ax); ay = fmaf(bf_hi(u0), n0, ay);
    }

    float2 b = ((const float2*)bias)[lane];
    ax += b.x; ay += b.y;
    if (do_relu) { ax = fmaxf(ax, 0.f); ay = fmaxf(ay, 0.f); }
    float2 o; o.x = ax; o.y = ay;
    ((float2*)O)[(size_t)i * 64 + lane] = o;
}

// ---------------- Softmax over K=100 (logits stored padded to 128) ----------------

__launch_bounds__(256)
__global__ void softmax_kernel(const float* __restrict__ L, float* __restrict__ O, int n) {
    int wid = threadIdx.x >> 6, lane = threadIdx.x & 63;
    int row = blockIdx.x * 4 + wid;
    if (row >= n) return;
    const float* lr = L + (size_t)row * 128;
    float v0 = (lane < KOUT) ? lr[lane] : -1e30f;
    float v1 = (lane + 64 < KOUT) ? lr[lane + 64] : -1e30f;
    float m = fmaxf(v0, v1);
    for (int off = 32; off > 0; off >>= 1) m = fmaxf(m, __shfl_xor(m, off));
    float e0 = (lane < KOUT) ? __expf(v0 - m) : 0.f;
    float e1 = (lane + 64 < KOUT) ? __expf(v1 - m) : 0.f;
    float s = e0 + e1;
    for (int off = 32; off > 0; off >>= 1) s += __shfl_xor(s, off);
    float inv = 1.f / s;
    if (lane < KOUT) O[(size_t)row * KOUT + lane] = e0 * inv;
    if (lane + 64 < KOUT) O[(size_t)row * KOUT + lane + 64] = e1 * inv;
}

// ---------------- launch ----------------

extern "C" void kernel_launch(void* const* d_in, const int* in_sizes, int n_in,
                              void* d_out, int out_size, void* d_ws, size_t ws_size,
                              hipStream_t stream) {
    const float* x  = (const float*)d_in[0];
    const int*   ei = (const int*)d_in[1];     // [2,E] int32
    const float* W1 = (const float*)d_in[2];
    const float* b1 = (const float*)d_in[3];
    const float* W2 = (const float*)d_in[4];
    const float* b2 = (const float*)d_in[5];
    const float* Wa = (const float*)d_in[6];
    const float* ba = (const float*)d_in[7];
    float* out = (float*)d_out;

    int N = in_sizes[0] / D;
    int E = in_sizes[1] / 2;

    char* w = (char*)d_ws;
    size_t off = 0;
    auto carve = [&](size_t bytes) -> void* {
        void* p = w + off;
        off = (off + bytes + 255) & ~(size_t)255;
        return p;
    };
    int*   deg    = (int*)carve((size_t)N * 4);
    int*   cursor = (int*)carve((size_t)N * 4);
    float* dinv   = (float*)carve((size_t)N * 4);
    int*   rowptr = (int*)carve((size_t)N * 4);
    int*   bsums  = (int*)carve(1024);
    int*   csr    = (int*)carve((size_t)E * 4);
    float* wnorm  = (float*)carve((size_t)E * 4);
    float* wpad   = (float*)carve(128 * 128 * 4);
    float* bpad   = (float*)carve(512);
    unsigned int* Hb = (unsigned int*)carve((size_t)N * 64 * 4);   // bf16-packed, 256 B/row
    float* bufB   = (float*)carve((size_t)N * D * 4);
    float* bufL   = (float*)carve((size_t)N * D * 4);
    (void)ws_size; (void)n_in; (void)out_size;

    int nbN = (N + 255) / 256;
    int nbE = (E + 255) / 256;
    int nbScan = (N + 1023) / 1024;
    int nbNode4 = (N + 3) / 4;
    int nbGemm = (N + 63) / 64;

    init_kernel<<<nbN, 256, 0, stream>>>(deg, cursor, N);
    count_kernel<<<nbE, 256, 0, stream>>>(ei, deg, E);
    dinv_kernel<<<nbN, 256, 0, stream>>>(deg, dinv, N);
    scan_block_kernel<<<nbScan, 256, 0, stream>>>(deg, rowptr, bsums, N);
    scan_total_kernel<<<1, 64, 0, stream>>>(bsums, nbScan);
    scan_add_kernel<<<nbN, 256, 0, stream>>>(rowptr, bsums, N);
    scatter_kernel<<<nbE, 256, 0, stream>>>(ei, rowptr, cursor, dinv, csr, wnorm, E);
    prep_wa_kernel<<<64, 256, 0, stream>>>(Wa, ba, wpad, bpad);

    // layer 1: lin (bf16 out) -> aggregate(+b1, relu) f32
    gemm128_kernel<<<nbGemm, 256, 0, stream>>>(x, W1, nullptr, Hb, N, 1);
    aggregate_kernel<<<nbNode4, 256, 0, stream>>>(Hb, csr, wnorm, rowptr, deg, dinv, b1, bufB, N, 1);
    // layer 2
    gemm128_kernel<<<nbGemm, 256, 0, stream>>>(bufB, W2, nullptr, Hb, N, 1);
    aggregate_kernel<<<nbNode4, 256, 0, stream>>>(Hb, csr, wnorm, rowptr, deg, dinv, b2, bufB, N, 0);
    // attention logits (padded to 128 cols, f32) + softmax
    gemm128_kernel<<<nbGemm, 256, 0, stream>>>(bufB, wpad, bpad, bufL, N, 0);
    softmax_kernel<<<nbNode4, 256, 0, stream>>>(bufL, out, N);
}

// Round 3
// 474.613 us; speedup vs baseline: 1.2615x; 1.0501x over previous
//
#include <hip/hip_runtime.h>

#define D 128
#define KOUT 100

// ---------------- bf16 pack/unpack helpers ----------------
// uint holds feature pair: low 16 bits = even feature, high 16 = odd feature.

__device__ inline float bf_lo(unsigned int u) { return __uint_as_float(u << 16); }
__device__ inline float bf_hi(unsigned int u) { return __uint_as_float(u & 0xFFFF0000u); }

__device__ inline unsigned int pack_bf(float a, float b) {
    unsigned int ua = __float_as_uint(a);
    unsigned int ub = __float_as_uint(b);
    ua = ua + 0x7FFFu + ((ua >> 16) & 1u);   // RNE
    ub = ub + 0x7FFFu + ((ub >> 16) & 1u);
    return (ua >> 16) | (ub & 0xFFFF0000u);
}

// ---------------- CSR build ----------------

__global__ void init_kernel(int* __restrict__ deg, int* __restrict__ cursor, int n) {
    int i = blockIdx.x * blockDim.x + threadIdx.x;
    if (i < n) { deg[i] = 1; cursor[i] = 0; }   // deg starts at 1 for self-loop
}

__global__ void count_kernel(const int* __restrict__ ei, int* __restrict__ deg, int E) {
    int e = blockIdx.x * blockDim.x + threadIdx.x;
    if (e < E) {
        int d = ei[E + e];          // dst row
        atomicAdd(&deg[d], 1);
    }
}

__global__ void dinv_kernel(const int* __restrict__ deg, float* __restrict__ dinv, int n) {
    int i = blockIdx.x * blockDim.x + threadIdx.x;
    if (i < n) dinv[i] = rsqrtf((float)deg[i]);   // deg >= 1 always (self-loop)
}

// exclusive scan of counts (deg[i]-1) -> rowptr, 1024 elems per block
__global__ void scan_block_kernel(const int* __restrict__ deg, int* __restrict__ rowptr,
                                  int* __restrict__ bsums, int n) {
    __shared__ int sd[256];
    int tid = threadIdx.x;
    int base = blockIdx.x * 1024 + tid * 4;
    int v[4];
    int sum = 0;
#pragma unroll
    for (int q = 0; q < 4; q++) {
        int idx = base + q;
        int c = (idx < n) ? (deg[idx] - 1) : 0;
        v[q] = sum;
        sum += c;
    }
    sd[tid] = sum;
    __syncthreads();
    for (int off = 1; off < 256; off <<= 1) {
        int t = (tid >= off) ? sd[tid - off] : 0;
        __syncthreads();
        sd[tid] += t;
        __syncthreads();
    }
    int excl = sd[tid] - sum;
#pragma unroll
    for (int q = 0; q < 4; q++) {
        int idx = base + q;
        if (idx < n) rowptr[idx] = excl + v[q];
    }
    if (tid == 255) bsums[blockIdx.x] = sd[255];
}

__global__ void scan_total_kernel(int* __restrict__ bsums, int nb) {
    if (threadIdx.x == 0 && blockIdx.x == 0) {
        int run = 0;
        for (int b = 0; b < nb; b++) { int t = bsums[b]; bsums[b] = run; run += t; }
    }
}

__global__ void scan_add_kernel(int* __restrict__ rowptr, const int* __restrict__ bsums, int n) {
    int i = blockIdx.x * blockDim.x + threadIdx.x;
    if (i < n) rowptr[i] += bsums[i >> 10];
}

// one 4B store per edge (wnorm removed — aggregate recomputes from dinv, L2-resident)
__global__ void scatter_kernel(const int* __restrict__ ei, const int* __restrict__ rowptr,
                               int* __restrict__ cursor, int* __restrict__ csr, int E) {
    int e = blockIdx.x * blockDim.x + threadIdx.x;
    if (e < E) {
        int s = ei[e];
        int d = ei[E + e];
        int p = atomicAdd(&cursor[d], 1);
        csr[rowptr[d] + p] = s;
    }
}

__global__ void prep_wa_kernel(const float* __restrict__ Wa, const float* __restrict__ ba,
                               float* __restrict__ wpad, float* __restrict__ bpad) {
    int idx = blockIdx.x * blockDim.x + threadIdx.x;
    if (idx < 128 * 128) {
        int k = idx >> 7, j = idx & 127;
        wpad[idx] = (j < KOUT) ? Wa[k * KOUT + j] : 0.f;
    }
    if (idx < 128) bpad[idx] = (idx < KOUT) ? ba[idx] : 0.f;
}

// ---------------- GEMM: Y[n,128] = X[n,128] @ W[128,128] (+bias) ----------------
// block 256 threads, tile 64 rows x 128 cols; thread = 8 rows x 4 cols

__device__ inline void fma4(float4& a, float s, const float4& w) {
    a.x = fmaf(s, w.x, a.x);
    a.y = fmaf(s, w.y, a.y);
    a.z = fmaf(s, w.z, a.z);
    a.w = fmaf(s, w.w, a.w);
}

__launch_bounds__(256)
__global__ void gemm128_kernel(const float* __restrict__ X, const float* __restrict__ W,
                               const float* __restrict__ bias, void* __restrict__ Y,
                               int nrows, int out_bf16) {
    __shared__ float Xs[64 * 128];
    int tid = threadIdx.x;
    int tx = tid & 31;       // col group: cols 4*tx .. 4*tx+3
    int ty = tid >> 5;       // row group: rows 8*ty .. 8*ty+7
    int r0 = blockIdx.x * 64;

    const float4* X4 = (const float4*)X;
    float4* Xs4 = (float4*)Xs;
#pragma unroll
    for (int it = 0; it < 8; it++) {
        int q = it * 256 + tid;
        int row = q >> 5, c4 = q & 31;
        float4 val = make_float4(0.f, 0.f, 0.f, 0.f);
        if (r0 + row < nrows) val = X4[(size_t)(r0 + row) * 32 + c4];
        Xs4[q] = val;
    }
    __syncthreads();

    const float4* W4 = (const float4*)W;
    float4 acc[8];
#pragma unroll
    for (int r = 0; r < 8; r++) acc[r] = make_float4(0.f, 0.f, 0.f, 0.f);

    for (int k = 0; k < 128; k += 4) {
        float4 w0 = W4[(k + 0) * 32 + tx];
        float4 w1 = W4[(k + 1) * 32 + tx];
        float4 w2 = W4[(k + 2) * 32 + tx];
        float4 w3 = W4[(k + 3) * 32 + tx];
#pragma unroll
        for (int r = 0; r < 8; r++) {
            float4 xv = Xs4[(ty * 8 + r) * 32 + (k >> 2)];
            fma4(acc[r], xv.x, w0);
            fma4(acc[r], xv.y, w1);
            fma4(acc[r], xv.z, w2);
            fma4(acc[r], xv.w, w3);
        }
    }

    float4 bb = make_float4(0.f, 0.f, 0.f, 0.f);
    if (bias) bb = ((const float4*)bias)[tx];
#pragma unroll
    for (int r = 0; r < 8; r++) {
        int row = r0 + ty * 8 + r;
        if (row < nrows) {
            float4 o;
            o.x = acc[r].x + bb.x;
            o.y = acc[r].y + bb.y;
            o.z = acc[r].z + bb.z;
            o.w = acc[r].w + bb.w;
            if (out_bf16) {
                uint2 u;
                u.x = pack_bf(o.x, o.y);
                u.y = pack_bf(o.z, o.w);
                ((uint2*)Y)[(size_t)row * 32 + tx] = u;
            } else {
                ((float4*)Y)[(size_t)row * 32 + tx] = o;
            }
        }
    }
}

// ---------------- Aggregate: O[i] = sum_{e:dst=i} Hb[src]*dinv[src]*dinv[i] + Hb[i]*dinv^2 + b
// one wave per node; H stored bf16-packed (uint per 2 features), lane = 1 uint = 2 feats
// f32 accumulate; 8 independent gathers in flight to hide L3 latency

__launch_bounds__(256)
__global__ void aggregate_kernel(const unsigned int* __restrict__ Hb, const int* __restrict__ csr,
                                 const int* __restrict__ rowptr, const int* __restrict__ deg,
                                 const float* __restrict__ dinv, const float* __restrict__ bias,
                                 float* __restrict__ O, int n, int do_relu) {
    int wid = threadIdx.x >> 6, lane = threadIdx.x & 63;
    int i = blockIdx.x * 4 + wid;
    if (i >= n) return;

    float di = dinv[i];
    float sl = di * di;
    unsigned int us = Hb[(size_t)i * 64 + lane];
    float ax = bf_lo(us) * sl;
    float ay = bf_hi(us) * sl;

    const int* cp = csr + rowptr[i];
    int cnt = deg[i] - 1;
    int e = 0;
    for (; e + 7 < cnt; e += 8) {
        int s[8];
        unsigned int u[8];
        float nn[8];
#pragma unroll
        for (int q = 0; q < 8; q++) s[q] = cp[e + q];
#pragma unroll
        for (int q = 0; q < 8; q++) {
            u[q] = Hb[(size_t)s[q] * 64 + lane];
            nn[q] = dinv[s[q]];                   // wave-uniform address -> broadcast
        }
#pragma unroll
        for (int q = 0; q < 8; q++) {
            float w = nn[q] * di;
            ax = fmaf(bf_lo(u[q]), w, ax);
            ay = fmaf(bf_hi(u[q]), w, ay);
        }
    }
    for (; e < cnt; e++) {
        int s0 = cp[e];
        unsigned int u0 = Hb[(size_t)s0 * 64 + lane];
        float w = dinv[s0] * di;
        ax = fmaf(bf_lo(u0), w, ax);
        ay = fmaf(bf_hi(u0), w, ay);
    }

    float2 b = ((const float2*)bias)[lane];
    ax += b.x; ay += b.y;
    if (do_relu) { ax = fmaxf(ax, 0.f); ay = fmaxf(ay, 0.f); }
    float2 o; o.x = ax; o.y = ay;
    ((float2*)O)[(size_t)i * 64 + lane] = o;
}

// ---------------- Softmax over K=100 (logits stored padded to 128) ----------------

__launch_bounds__(256)
__global__ void softmax_kernel(const float* __restrict__ L, float* __restrict__ O, int n) {
    int wid = threadIdx.x >> 6, lane = threadIdx.x & 63;
    int row = blockIdx.x * 4 + wid;
    if (row >= n) return;
    const float* lr = L + (size_t)row * 128;
    float v0 = (lane < KOUT) ? lr[lane] : -1e30f;
    float v1 = (lane + 64 < KOUT) ? lr[lane + 64] : -1e30f;
    float m = fmaxf(v0, v1);
    for (int off = 32; off > 0; off >>= 1) m = fmaxf(m, __shfl_xor(m, off));
    float e0 = (lane < KOUT) ? __expf(v0 - m) : 0.f;
    float e1 = (lane + 64 < KOUT) ? __expf(v1 - m) : 0.f;
    float s = e0 + e1;
    for (int off = 32; off > 0; off >>= 1) s += __shfl_xor(s, off);
    float inv = 1.f / s;
    if (lane < KOUT) O[(size_t)row * KOUT + lane] = e0 * inv;
    if (lane + 64 < KOUT) O[(size_t)row * KOUT + lane + 64] = e1 * inv;
}

// ---------------- launch ----------------

extern "C" void kernel_launch(void* const* d_in, const int* in_sizes, int n_in,
                              void* d_out, int out_size, void* d_ws, size_t ws_size,
                              hipStream_t stream) {
    const float* x  = (const float*)d_in[0];
    const int*   ei = (const int*)d_in[1];     // [2,E] int32
    const float* W1 = (const float*)d_in[2];
    const float* b1 = (const float*)d_in[3];
    const float* W2 = (const float*)d_in[4];
    const float* b2 = (const float*)d_in[5];
    const float* Wa = (const float*)d_in[6];
    const float* ba = (const float*)d_in[7];
    float* out = (float*)d_out;

    int N = in_sizes[0] / D;
    int E = in_sizes[1] / 2;

    char* w = (char*)d_ws;
    size_t off = 0;
    auto carve = [&](size_t bytes) -> void* {
        void* p = w + off;
        off = (off + bytes + 255) & ~(size_t)255;
        return p;
    };
    int*   deg    = (int*)carve((size_t)N * 4);
    int*   cursor = (int*)carve((size_t)N * 4);
    float* dinv   = (float*)carve((size_t)N * 4);
    int*   rowptr = (int*)carve((size_t)N * 4);
    int*   bsums  = (int*)carve(1024);
    int*   csr    = (int*)carve((size_t)E * 4);
    float* wpad   = (float*)carve(128 * 128 * 4);
    float* bpad   = (float*)carve(512);
    unsigned int* Hb = (unsigned int*)carve((size_t)N * 64 * 4);   // bf16-packed, 256 B/row
    float* bufB   = (float*)carve((size_t)N * D * 4);
    float* bufL   = (float*)carve((size_t)N * D * 4);
    (void)ws_size; (void)n_in; (void)out_size;

    int nbN = (N + 255) / 256;
    int nbE = (E + 255) / 256;
    int nbScan = (N + 1023) / 1024;
    int nbNode4 = (N + 3) / 4;
    int nbGemm = (N + 63) / 64;

    init_kernel<<<nbN, 256, 0, stream>>>(deg, cursor, N);
    count_kernel<<<nbE, 256, 0, stream>>>(ei, deg, E);
    dinv_kernel<<<nbN, 256, 0, stream>>>(deg, dinv, N);
    scan_block_kernel<<<nbScan, 256, 0, stream>>>(deg, rowptr, bsums, N);
    scan_total_kernel<<<1, 64, 0, stream>>>(bsums, nbScan);
    scan_add_kernel<<<nbN, 256, 0, stream>>>(rowptr, bsums, N);
    scatter_kernel<<<nbE, 256, 0, stream>>>(ei, rowptr, cursor, csr, E);
    prep_wa_kernel<<<64, 256, 0, stream>>>(Wa, ba, wpad, bpad);

    // layer 1: lin (bf16 out) -> aggregate(+b1, relu) f32
    gemm128_kernel<<<nbGemm, 256, 0, stream>>>(x, W1, nullptr, Hb, N, 1);
    aggregate_kernel<<<nbNode4, 256, 0, stream>>>(Hb, csr, rowptr, deg, dinv, b1, bufB, N, 1);
    // layer 2
    gemm128_kernel<<<nbGemm, 256, 0, stream>>>(bufB, W2, nullptr, Hb, N, 1);
    aggregate_kernel<<<nbNode4, 256, 0, stream>>>(Hb, csr, rowptr, deg, dinv, b2, bufB, N, 0);
    // attention logits (padded to 128 cols, f32) + softmax
    gemm128_kernel<<<nbGemm, 256, 0, stream>>>(bufB, wpad, bpad, bufL, N, 0);
    softmax_kernel<<<nbNode4, 256, 0, stream>>>(bufL, out, N);
}

// Round 4
// 365.890 us; speedup vs baseline: 1.6363x; 1.2971x over previous
//
#include <hip/hip_runtime.h>

#define D 128
#define KOUT 100
#define CHUNK 4096   // edges per pass-1 block

// ---------------- bf16 pack/unpack helpers ----------------
// uint holds feature pair: low 16 bits = even feature, high 16 = odd feature.

__device__ inline float bf_lo(unsigned int u) { return __uint_as_float(u << 16); }
__device__ inline float bf_hi(unsigned int u) { return __uint_as_float(u & 0xFFFF0000u); }

__device__ inline unsigned int pack_bf(float a, float b) {
    unsigned int ua = __float_as_uint(a);
    unsigned int ub = __float_as_uint(b);
    ua = ua + 0x7FFFu + ((ua >> 16) & 1u);   // RNE
    ub = ub + 0x7FFFu + ((ub >> 16) & 1u);
    return (ua >> 16) | (ub & 0xFFFF0000u);
}

// ---------------- CSR build: two-pass bucket radix partition ----------------
// bucket = dst >> 8 (256 nodes per bucket; requires N <= 65536, here N=50000 -> 196 buckets)
// packed edge record: bits[23:0] = src, bits[31:24] = dst & 255

__global__ void zero_kernel(int* __restrict__ p, int n) {
    int i = blockIdx.x * blockDim.x + threadIdx.x;
    if (i < n) p[i] = 0;
}

// Pass 1: per-block LDS counting sort by bucket, coalesced run writes.
__launch_bounds__(256)
__global__ void bucket_pass1(const int* __restrict__ ei, int E, int nbuck, int cap,
                             int* __restrict__ bcur, unsigned int* __restrict__ bdata) {
    __shared__ int hist[256];
    __shared__ int sc[256];
    __shared__ int pfx[257];
    __shared__ int cur[256];
    __shared__ int gbase[256];
    __shared__ unsigned int lbuf[CHUNK];   // 16 KB

    int tid = threadIdx.x;
    int base = blockIdx.x * CHUNK;
    int cnt = E - base; if (cnt > CHUNK) cnt = CHUNK;

    for (int b = tid; b < 256; b += 256) hist[b] = 0;
    __syncthreads();

    int src[CHUNK / 256];
    int dst[CHUNK / 256];
#pragma unroll
    for (int q = 0; q < CHUNK / 256; q++) {
        int li = tid + q * 256;
        if (li < cnt) {
            src[q] = ei[base + li];
            dst[q] = ei[E + base + li];
            atomicAdd(&hist[dst[q] >> 8], 1);
        }
    }
    __syncthreads();

    // exclusive prefix over hist
    int v = hist[tid];
    sc[tid] = v;
    __syncthreads();
    for (int off = 1; off < 256; off <<= 1) {
        int t = (tid >= off) ? sc[tid - off] : 0;
        __syncthreads();
        sc[tid] += t;
        __syncthreads();
    }
    int excl = sc[tid] - v;
    pfx[tid] = excl;
    cur[tid] = excl;
    gbase[tid] = 0;
    if (tid < nbuck && v > 0) gbase[tid] = atomicAdd(&bcur[tid], v);
    if (tid == 0) pfx[nbuck] = cnt;
    __syncthreads();

    // place into LDS grouped by bucket
#pragma unroll
    for (int q = 0; q < CHUNK / 256; q++) {
        int li = tid + q * 256;
        if (li < cnt) {
            int b = dst[q] >> 8;
            int p = atomicAdd(&cur[b], 1);
            lbuf[p] = (unsigned int)src[q] | ((unsigned int)(dst[q] & 255) << 24);
        }
    }
    __syncthreads();

    // write runs: consecutive p -> consecutive global within each run
    for (int p = tid; p < cnt; p += 256) {
        int lo = 0, hi = nbuck - 1;
        while (lo < hi) {
            int mid = (lo + hi + 1) >> 1;
            if (pfx[mid] <= p) lo = mid; else hi = mid - 1;
        }
        int b = lo;
        bdata[(size_t)b * cap + gbase[b] + (p - pfx[b])] = lbuf[p];
    }
}

// Pass 2a: per-bucket degree histogram (+1 self-loop) and dinv.
__launch_bounds__(256)
__global__ void bucket_deg(const unsigned int* __restrict__ bdata, const int* __restrict__ bcur,
                           int cap, int* __restrict__ deg, float* __restrict__ dinv, int n) {
    __shared__ int hist[256];
    int b = blockIdx.x, tid = threadIdx.x;
    hist[tid] = 0;
    __syncthreads();
    int cnt = bcur[b];
    const unsigned int* p = bdata + (size_t)b * cap;
    for (int e = tid; e < cnt; e += 256) atomicAdd(&hist[p[e] >> 24], 1);
    __syncthreads();
    int node = b * 256 + tid;
    if (node < n) {
        int d = hist[tid] + 1;
        deg[node] = d;
        dinv[node] = rsqrtf((float)d);
    }
}

// Pass 2b: per-bucket scatter into compact CSR via LDS cursors.
__launch_bounds__(256)
__global__ void bucket_scatter(const unsigned int* __restrict__ bdata, const int* __restrict__ bcur,
                               int cap, const int* __restrict__ rowptr, int* __restrict__ csr, int n) {
    __shared__ int cur[256];
    int b = blockIdx.x, tid = threadIdx.x;
    int node = b * 256 + tid;
    cur[tid] = (node < n) ? rowptr[node] : 0;
    __syncthreads();
    int cnt = bcur[b];
    const unsigned int* p = bdata + (size_t)b * cap;
    for (int e = tid; e < cnt; e += 256) {
        unsigned int u = p[e];
        int pos = atomicAdd(&cur[u >> 24], 1);
        csr[pos] = (int)(u & 0xFFFFFFu);
    }
}

// ---------------- scan of (deg-1) -> rowptr ----------------

__global__ void scan_block_kernel(const int* __restrict__ deg, int* __restrict__ rowptr,
                                  int* __restrict__ bsums, int n) {
    __shared__ int sd[256];
    int tid = threadIdx.x;
    int base = blockIdx.x * 1024 + tid * 4;
    int v[4];
    int sum = 0;
#pragma unroll
    for (int q = 0; q < 4; q++) {
        int idx = base + q;
        int c = (idx < n) ? (deg[idx] - 1) : 0;
        v[q] = sum;
        sum += c;
    }
    sd[tid] = sum;
    __syncthreads();
    for (int off = 1; off < 256; off <<= 1) {
        int t = (tid >= off) ? sd[tid - off] : 0;
        __syncthreads();
        sd[tid] += t;
        __syncthreads();
    }
    int excl = sd[tid] - sum;
#pragma unroll
    for (int q = 0; q < 4; q++) {
        int idx = base + q;
        if (idx < n) rowptr[idx] = excl + v[q];
    }
    if (tid == 255) bsums[blockIdx.x] = sd[255];
}

__global__ void scan_total_kernel(int* __restrict__ bsums, int nb) {
    if (threadIdx.x == 0 && blockIdx.x == 0) {
        int run = 0;
        for (int b = 0; b < nb; b++) { int t = bsums[b]; bsums[b] = run; run += t; }
    }
}

__global__ void scan_add_kernel(int* __restrict__ rowptr, const int* __restrict__ bsums, int n) {
    int i = blockIdx.x * blockDim.x + threadIdx.x;
    if (i < n) rowptr[i] += bsums[i >> 10];
}

__global__ void prep_wa_kernel(const float* __restrict__ Wa, const float* __restrict__ ba,
                               float* __restrict__ wpad, float* __restrict__ bpad) {
    int idx = blockIdx.x * blockDim.x + threadIdx.x;
    if (idx < 128 * 128) {
        int k = idx >> 7, j = idx & 127;
        wpad[idx] = (j < KOUT) ? Wa[k * KOUT + j] : 0.f;
    }
    if (idx < 128) bpad[idx] = (idx < KOUT) ? ba[idx] : 0.f;
}

// ---------------- GEMM: Y[n,128] = X[n,128] @ W[128,128] (+bias) ----------------

__device__ inline void fma4(float4& a, float s, const float4& w) {
    a.x = fmaf(s, w.x, a.x);
    a.y = fmaf(s, w.y, a.y);
    a.z = fmaf(s, w.z, a.z);
    a.w = fmaf(s, w.w, a.w);
}

__launch_bounds__(256)
__global__ void gemm128_kernel(const float* __restrict__ X, const float* __restrict__ W,
                               const float* __restrict__ bias, void* __restrict__ Y,
                               int nrows, int out_bf16) {
    __shared__ float Xs[64 * 128];
    int tid = threadIdx.x;
    int tx = tid & 31;
    int ty = tid >> 5;
    int r0 = blockIdx.x * 64;

    const float4* X4 = (const float4*)X;
    float4* Xs4 = (float4*)Xs;
#pragma unroll
    for (int it = 0; it < 8; it++) {
        int q = it * 256 + tid;
        int row = q >> 5, c4 = q & 31;
        float4 val = make_float4(0.f, 0.f, 0.f, 0.f);
        if (r0 + row < nrows) val = X4[(size_t)(r0 + row) * 32 + c4];
        Xs4[q] = val;
    }
    __syncthreads();

    const float4* W4 = (const float4*)W;
    float4 acc[8];
#pragma unroll
    for (int r = 0; r < 8; r++) acc[r] = make_float4(0.f, 0.f, 0.f, 0.f);

    for (int k = 0; k < 128; k += 4) {
        float4 w0 = W4[(k + 0) * 32 + tx];
        float4 w1 = W4[(k + 1) * 32 + tx];
        float4 w2 = W4[(k + 2) * 32 + tx];
        float4 w3 = W4[(k + 3) * 32 + tx];
#pragma unroll
        for (int r = 0; r < 8; r++) {
            float4 xv = Xs4[(ty * 8 + r) * 32 + (k >> 2)];
            fma4(acc[r], xv.x, w0);
            fma4(acc[r], xv.y, w1);
            fma4(acc[r], xv.z, w2);
            fma4(acc[r], xv.w, w3);
        }
    }

    float4 bb = make_float4(0.f, 0.f, 0.f, 0.f);
    if (bias) bb = ((const float4*)bias)[tx];
#pragma unroll
    for (int r = 0; r < 8; r++) {
        int row = r0 + ty * 8 + r;
        if (row < nrows) {
            float4 o;
            o.x = acc[r].x + bb.x;
            o.y = acc[r].y + bb.y;
            o.z = acc[r].z + bb.z;
            o.w = acc[r].w + bb.w;
            if (out_bf16) {
                uint2 u;
                u.x = pack_bf(o.x, o.y);
                u.y = pack_bf(o.z, o.w);
                ((uint2*)Y)[(size_t)row * 32 + tx] = u;
            } else {
                ((float4*)Y)[(size_t)row * 32 + tx] = o;
            }
        }
    }
}

// ---------------- Aggregate ----------------

__launch_bounds__(256)
__global__ void aggregate_kernel(const unsigned int* __restrict__ Hb, const int* __restrict__ csr,
                                 const int* __restrict__ rowptr, const int* __restrict__ deg,
                                 const float* __restrict__ dinv, const float* __restrict__ bias,
                                 float* __restrict__ O, int n, int do_relu) {
    int wid = threadIdx.x >> 6, lane = threadIdx.x & 63;
    int i = blockIdx.x * 4 + wid;
    if (i >= n) return;

    float di = dinv[i];
    float sl = di * di;
    unsigned int us = Hb[(size_t)i * 64 + lane];
    float ax = bf_lo(us) * sl;
    float ay = bf_hi(us) * sl;

    const int* cp = csr + rowptr[i];
    int cnt = deg[i] - 1;
    int e = 0;
    for (; e + 7 < cnt; e += 8) {
        int s[8];
        unsigned int u[8];
        float nn[8];
#pragma unroll
        for (int q = 0; q < 8; q++) s[q] = cp[e + q];
#pragma unroll
        for (int q = 0; q < 8; q++) {
            u[q] = Hb[(size_t)s[q] * 64 + lane];
            nn[q] = dinv[s[q]];
        }
#pragma unroll
        for (int q = 0; q < 8; q++) {
            float w = nn[q] * di;
            ax = fmaf(bf_lo(u[q]), w, ax);
            ay = fmaf(bf_hi(u[q]), w, ay);
        }
    }
    for (; e < cnt; e++) {
        int s0 = cp[e];
        unsigned int u0 = Hb[(size_t)s0 * 64 + lane];
        float w = dinv[s0] * di;
        ax = fmaf(bf_lo(u0), w, ax);
        ay = fmaf(bf_hi(u0), w, ay);
    }

    float2 b = ((const float2*)bias)[lane];
    ax += b.x; ay += b.y;
    if (do_relu) { ax = fmaxf(ax, 0.f); ay = fmaxf(ay, 0.f); }
    float2 o; o.x = ax; o.y = ay;
    ((float2*)O)[(size_t)i * 64 + lane] = o;
}

// ---------------- Softmax over K=100 ----------------

__launch_bounds__(256)
__global__ void softmax_kernel(const float* __restrict__ L, float* __restrict__ O, int n) {
    int wid = threadIdx.x >> 6, lane = threadIdx.x & 63;
    int row = blockIdx.x * 4 + wid;
    if (row >= n) return;
    const float* lr = L + (size_t)row * 128;
    float v0 = (lane < KOUT) ? lr[lane] : -1e30f;
    float v1 = (lane + 64 < KOUT) ? lr[lane + 64] : -1e30f;
    float m = fmaxf(v0, v1);
    for (int off = 32; off > 0; off >>= 1) m = fmaxf(m, __shfl_xor(m, off));
    float e0 = (lane < KOUT) ? __expf(v0 - m) : 0.f;
    float e1 = (lane + 64 < KOUT) ? __expf(v1 - m) : 0.f;
    float s = e0 + e1;
    for (int off = 32; off > 0; off >>= 1) s += __shfl_xor(s, off);
    float inv = 1.f / s;
    if (lane < KOUT) O[(size_t)row * KOUT + lane] = e0 * inv;
    if (lane + 64 < KOUT) O[(size_t)row * KOUT + lane + 64] = e1 * inv;
}

// ---------------- launch ----------------

extern "C" void kernel_launch(void* const* d_in, const int* in_sizes, int n_in,
                              void* d_out, int out_size, void* d_ws, size_t ws_size,
                              hipStream_t stream) {
    const float* x  = (const float*)d_in[0];
    const int*   ei = (const int*)d_in[1];     // [2,E] int32
    const float* W1 = (const float*)d_in[2];
    const float* b1 = (const float*)d_in[3];
    const float* W2 = (const float*)d_in[4];
    const float* b2 = (const float*)d_in[5];
    const float* Wa = (const float*)d_in[6];
    const float* ba = (const float*)d_in[7];
    float* out = (float*)d_out;

    int N = in_sizes[0] / D;
    int E = in_sizes[1] / 2;

    int nbuck = (N + 255) >> 8;                       // 196 for N=50000 (must be <=256)
    int cap = ((E / nbuck) + 2048 + 63) & ~63;        // per-bucket capacity, >23 sigma slack

    char* w = (char*)d_ws;
    size_t off = 0;
    auto carve = [&](size_t bytes) -> void* {
        void* p = w + off;
        off = (off + bytes + 255) & ~(size_t)255;
        return p;
    };
    int*   deg    = (int*)carve((size_t)N * 4);
    float* dinv   = (float*)carve((size_t)N * 4);
    int*   rowptr = (int*)carve((size_t)N * 4);
    int*   bsums  = (int*)carve(1024);
    int*   bcur   = (int*)carve(256 * 4);
    unsigned int* bdata = (unsigned int*)carve((size_t)nbuck * cap * 4);
    int*   csr    = (int*)carve((size_t)E * 4);
    float* wpad   = (float*)carve(128 * 128 * 4);
    float* bpad   = (float*)carve(512);
    unsigned int* Hb = (unsigned int*)carve((size_t)N * 64 * 4);   // bf16-packed, 256 B/row
    float* bufB   = (float*)carve((size_t)N * D * 4);
    float* bufL   = (float*)carve((size_t)N * D * 4);
    (void)ws_size; (void)n_in; (void)out_size;

    int nbN = (N + 255) / 256;
    int nbScan = (N + 1023) / 1024;
    int nbNode4 = (N + 3) / 4;
    int nbGemm = (N + 63) / 64;
    int nbP1 = (E + CHUNK - 1) / CHUNK;

    zero_kernel<<<1, 256, 0, stream>>>(bcur, 256);
    bucket_pass1<<<nbP1, 256, 0, stream>>>(ei, E, nbuck, cap, bcur, bdata);
    bucket_deg<<<nbuck, 256, 0, stream>>>(bdata, bcur, cap, deg, dinv, N);
    scan_block_kernel<<<nbScan, 256, 0, stream>>>(deg, rowptr, bsums, N);
    scan_total_kernel<<<1, 64, 0, stream>>>(bsums, nbScan);
    scan_add_kernel<<<nbN, 256, 0, stream>>>(rowptr, bsums, N);
    bucket_scatter<<<nbuck, 256, 0, stream>>>(bdata, bcur, cap, rowptr, csr, N);
    prep_wa_kernel<<<64, 256, 0, stream>>>(Wa, ba, wpad, bpad);

    // layer 1: lin (bf16 out) -> aggregate(+b1, relu) f32
    gemm128_kernel<<<nbGemm, 256, 0, stream>>>(x, W1, nullptr, Hb, N, 1);
    aggregate_kernel<<<nbNode4, 256, 0, stream>>>(Hb, csr, rowptr, deg, dinv, b1, bufB, N, 1);
    // layer 2
    gemm128_kernel<<<nbGemm, 256, 0, stream>>>(bufB, W2, nullptr, Hb, N, 1);
    aggregate_kernel<<<nbNode4, 256, 0, stream>>>(Hb, csr, rowptr, deg, dinv, b2, bufB, N, 0);
    // attention logits (padded to 128 cols, f32) + softmax
    gemm128_kernel<<<nbGemm, 256, 0, stream>>>(bufB, wpad, bpad, bufL, N, 0);
    softmax_kernel<<<nbNode4, 256, 0, stream>>>(bufL, out, N);
}